// Round 3
// baseline (2315.585 us; speedup 1.0000x reference)
//
#include <hip/hip_runtime.h>
#include <cstddef>

#define Cc 96
#define CH 384
#define Mtok 262144   // B*H*W = 16*128*128

static __device__ __forceinline__ float b2f(unsigned short s){
  union { unsigned u; float f; } v; v.u = ((unsigned)s) << 16; return v.f;
}
static __device__ __forceinline__ unsigned short f2b(float f){
  union { float f; unsigned u; } v; v.f = f;
  unsigned r = v.u + 0x7fffu + ((v.u >> 16) & 1u);
  return (unsigned short)(r >> 16);
}

// ---------------- K1: gate-H softmax weights  wh[5][Mloc] ----------------
__global__ __launch_bounds__(256) void k_gate_h(const float* __restrict__ x,
    const float* __restrict__ gh_w, const float* __restrict__ gh_b,
    float* __restrict__ wh, int base, int Mloc){
  int m = blockIdx.x*256 + threadIdx.x;
  const float* xr = x + (size_t)(base + m)*Cc;
  float l[5];
  #pragma unroll
  for (int s=0;s<5;++s) l[s] = gh_b[s];
  #pragma unroll
  for (int c=0;c<Cc;c+=4){
    float4 xv = *(const float4*)(xr+c);
    #pragma unroll
    for (int s=0;s<5;++s){
      float4 g = *(const float4*)(gh_w + s*Cc + c);
      l[s]=fmaf(xv.x,g.x,l[s]); l[s]=fmaf(xv.y,g.y,l[s]);
      l[s]=fmaf(xv.z,g.z,l[s]); l[s]=fmaf(xv.w,g.w,l[s]);
    }
  }
  float mx = fmaxf(fmaxf(fmaxf(l[0],l[1]),fmaxf(l[2],l[3])),l[4]);
  float sum=0.f;
  #pragma unroll
  for (int s=0;s<5;++s){ l[s]=__expf(l[s]-mx); sum+=l[s]; }
  float inv = 1.f/sum;
  #pragma unroll
  for (int s=0;s<5;++s) wh[(size_t)s*Mloc + m] = l[s]*inv;
}

// ---------------- K2: fused H-shift-mix + fc1 GEMM -> hid (bf16) ----------------
__global__ __launch_bounds__(256) void k_fc1(const float* __restrict__ x,
    const float* __restrict__ wh, const float* __restrict__ fc1w,
    const float* __restrict__ fc1b, unsigned short* __restrict__ hid,
    int base, int Mloc){
  __shared__ float As[64][100];
  __shared__ float Bs[96][64];
  const int tid = threadIdx.x;
  const int m0 = blockIdx.x*64;
  const int n0 = blockIdx.y*64;
  {
    int sr = tid>>2, sq = tid&3;
    int ml = m0 + sr;              // local token
    int gm = base + ml;            // global token
    int sh = (gm>>7)&127;          // h coordinate
    float swgt[5];
    #pragma unroll
    for (int i=0;i<5;++i){
      int h2 = sh - (i-2);
      swgt[i] = ((unsigned)h2 < 128u) ? wh[(size_t)i*Mloc + ml] : 0.f;
    }
    #pragma unroll
    for (int j=0;j<6;++j){
      int c = sq*24 + j*4;
      float4 a = make_float4(0.f,0.f,0.f,0.f);
      #pragma unroll
      for (int i=0;i<5;++i){
        if (swgt[i] != 0.f){
          float4 xv = *(const float4*)&x[(size_t)(gm - (i-2)*128)*Cc + c];
          a.x=fmaf(swgt[i],xv.x,a.x); a.y=fmaf(swgt[i],xv.y,a.y);
          a.z=fmaf(swgt[i],xv.z,a.z); a.w=fmaf(swgt[i],xv.w,a.w);
        }
      }
      *(float4*)&As[sr][c] = a;
    }
    int bk = tid>>4, bj = (tid&15)*4;
    #pragma unroll
    for (int p=0;p<6;++p){
      int k = p*16 + bk;
      *(float4*)&Bs[k][bj] = *(const float4*)&fc1w[(size_t)k*CH + n0 + bj];
    }
  }
  __syncthreads();
  const int tx = tid&15, ty = tid>>4;
  float acc[4][4] = {};
  for (int k=0;k<96;k+=4){
    float4 a[4], b[4];
    #pragma unroll
    for (int i=0;i<4;++i) a[i] = *(const float4*)&As[ty*4+i][k];
    #pragma unroll
    for (int kk=0;kk<4;++kk) b[kk] = *(const float4*)&Bs[k+kk][tx*4];
    #pragma unroll
    for (int kk=0;kk<4;++kk){
      #pragma unroll
      for (int i=0;i<4;++i){
        float av = (kk==0)?a[i].x:(kk==1)?a[i].y:(kk==2)?a[i].z:a[i].w;
        acc[i][0]=fmaf(av,b[kk].x,acc[i][0]);
        acc[i][1]=fmaf(av,b[kk].y,acc[i][1]);
        acc[i][2]=fmaf(av,b[kk].z,acc[i][2]);
        acc[i][3]=fmaf(av,b[kk].w,acc[i][3]);
      }
    }
  }
  float bb[4];
  #pragma unroll
  for (int j=0;j<4;++j) bb[j] = fc1b[n0 + tx*4 + j];
  #pragma unroll
  for (int i=0;i<4;++i){
    size_t m = (size_t)(m0 + ty*4 + i);
    ushort4 pk;
    pk.x = f2b(acc[i][0]+bb[0]);
    pk.y = f2b(acc[i][1]+bb[1]);
    pk.z = f2b(acc[i][2]+bb[2]);
    pk.w = f2b(acc[i][3]+bb[3]);
    *(ushort4*)&hid[m*CH + n0 + tx*4] = pk;
  }
}

// ---------------- K3: dwconv3x3 + bias + exact GELU + gate-W -> hid2, ww ----------------
__global__ __launch_bounds__(128) void k_dw(const unsigned short* __restrict__ hid,
    const float* __restrict__ dww, const float* __restrict__ dwb,
    const float* __restrict__ gww, const float* __restrict__ gwb,
    unsigned short* __restrict__ hid2, float* __restrict__ ww, int Mloc){
  const int m = blockIdx.x;          // local token; (m>>7)&127 == h for both paths
  const int h = (m>>7)&127, w = m&127;
  const int t = threadIdx.x;
  float part[5] = {0.f,0.f,0.f,0.f,0.f};
  #pragma unroll
  for (int cc=0;cc<3;++cc){
    int c = t + cc*128;
    float acc = dwb[c];
    #pragma unroll
    for (int kh=0;kh<3;++kh){
      int h2 = h + kh - 1;
      if ((unsigned)h2 < 128u){
        #pragma unroll
        for (int kw=0;kw<3;++kw){
          int w2 = w + kw - 1;
          if ((unsigned)w2 < 128u){
            float xv = b2f(hid[(size_t)(m + (kh-1)*128 + (kw-1))*CH + c]);
            acc = fmaf(xv, dww[c*9 + kh*3 + kw], acc);
          }
        }
      }
    }
    float g = 0.5f*acc*(1.f + erff(acc*0.70710678118654752f));
    hid2[(size_t)m*CH + c] = f2b(g);
    #pragma unroll
    for (int s=0;s<5;++s) part[s] = fmaf(g, gww[s*CH + c], part[s]);
  }
  __shared__ float red[5][2];
  #pragma unroll
  for (int s=0;s<5;++s){
    float v = part[s];
    #pragma unroll
    for (int off=32;off>0;off>>=1) v += __shfl_down(v, off, 64);
    if ((t&63)==0) red[s][t>>6] = v;
  }
  __syncthreads();
  if (t==0){
    float l[5];
    #pragma unroll
    for (int s=0;s<5;++s) l[s] = red[s][0] + red[s][1] + gwb[s];
    float mx = fmaxf(fmaxf(fmaxf(l[0],l[1]),fmaxf(l[2],l[3])),l[4]);
    float sum=0.f;
    #pragma unroll
    for (int s=0;s<5;++s){ l[s]=__expf(l[s]-mx); sum+=l[s]; }
    float inv=1.f/sum;
    #pragma unroll
    for (int s=0;s<5;++s) ww[(size_t)s*Mloc + m] = l[s]*inv;
  }
}

// ---------------- K4: fused W-shift-mix + fc2 GEMM -> out (f32) ----------------
__global__ __launch_bounds__(256) void k_fc2(const unsigned short* __restrict__ hid2,
    const float* __restrict__ ww, const float* __restrict__ fc2w,
    const float* __restrict__ fc2b, float* __restrict__ out,
    int base, int Mloc){
  __shared__ float As[64][68];
  __shared__ float Bs[64][96];
  const int tid = threadIdx.x;
  const int m0 = blockIdx.x*64;
  const int sr = tid>>2, sq = tid&3;
  const int ml = m0 + sr;            // local token
  const int gm = base + ml;          // global token
  const int swp = gm & 127;          // w coordinate
  float swgt[5];
  #pragma unroll
  for (int i=0;i<5;++i){
    int w2 = swp - (i-2);
    swgt[i] = ((unsigned)w2 < 128u) ? ww[(size_t)i*Mloc + ml] : 0.f;
  }
  const int tx = tid&15, ty = tid>>4;
  float acc[4][6] = {};
  for (int kb=0;kb<6;++kb){
    const int k0 = kb*64;
    #pragma unroll
    for (int j=0;j<4;++j){
      int k = sq*16 + j*4;
      float4 a = make_float4(0.f,0.f,0.f,0.f);
      #pragma unroll
      for (int i=0;i<5;++i){
        if (swgt[i] != 0.f){
          ushort4 hv = *(const ushort4*)&hid2[(size_t)(ml-(i-2))*CH + k0 + k];
          a.x=fmaf(swgt[i],b2f(hv.x),a.x);
          a.y=fmaf(swgt[i],b2f(hv.y),a.y);
          a.z=fmaf(swgt[i],b2f(hv.z),a.z);
          a.w=fmaf(swgt[i],b2f(hv.w),a.w);
        }
      }
      *(float4*)&As[sr][k] = a;
    }
    #pragma unroll
    for (int j=0;j<6;++j){
      *(float4*)&Bs[sr][sq*24 + j*4] = *(const float4*)&fc2w[(size_t)(k0+sr)*96 + sq*24 + j*4];
    }
    __syncthreads();
    for (int k=0;k<64;k+=4){
      float4 a[4];
      #pragma unroll
      for (int i=0;i<4;++i) a[i] = *(const float4*)&As[ty*4+i][k];
      #pragma unroll
      for (int kk=0;kk<4;++kk){
        float2 b0 = *(const float2*)&Bs[k+kk][tx*6];
        float2 b1 = *(const float2*)&Bs[k+kk][tx*6+2];
        float2 b2 = *(const float2*)&Bs[k+kk][tx*6+4];
        #pragma unroll
        for (int i=0;i<4;++i){
          float av = (kk==0)?a[i].x:(kk==1)?a[i].y:(kk==2)?a[i].z:a[i].w;
          acc[i][0]=fmaf(av,b0.x,acc[i][0]);
          acc[i][1]=fmaf(av,b0.y,acc[i][1]);
          acc[i][2]=fmaf(av,b1.x,acc[i][2]);
          acc[i][3]=fmaf(av,b1.y,acc[i][3]);
          acc[i][4]=fmaf(av,b2.x,acc[i][4]);
          acc[i][5]=fmaf(av,b2.y,acc[i][5]);
        }
      }
    }
    __syncthreads();
  }
  float bb[6];
  #pragma unroll
  for (int j=0;j<6;++j) bb[j] = fc2b[tx*6+j];
  #pragma unroll
  for (int i=0;i<4;++i){
    size_t m = (size_t)(base + m0 + ty*4 + i);
    float2 o0 = make_float2(acc[i][0]+bb[0], acc[i][1]+bb[1]);
    float2 o1 = make_float2(acc[i][2]+bb[2], acc[i][3]+bb[3]);
    float2 o2 = make_float2(acc[i][4]+bb[4], acc[i][5]+bb[5]);
    *(float2*)&out[m*96 + tx*6  ] = o0;
    *(float2*)&out[m*96 + tx*6+2] = o1;
    *(float2*)&out[m*96 + tx*6+4] = o2;
  }
}

extern "C" void kernel_launch(void* const* d_in, const int* in_sizes, int n_in,
                              void* d_out, int out_size, void* d_ws, size_t ws_size,
                              hipStream_t stream) {
  const float* x     = (const float*)d_in[0];
  const float* fc1_w = (const float*)d_in[3];
  const float* fc1_b = (const float*)d_in[4];
  const float* dw_w  = (const float*)d_in[5];
  const float* dw_b  = (const float*)d_in[6];
  const float* fc2_w = (const float*)d_in[7];
  const float* fc2_b = (const float*)d_in[8];
  const float* gh_w  = (const float*)d_in[9];
  const float* gh_b  = (const float*)d_in[10];
  const float* gw_w  = (const float*)d_in[11];
  const float* gw_b  = (const float*)d_in[12];
  float* out = (float*)d_out;

  // Full path needs: 2*5*M*4 + 2*M*384*2 bytes = 413.1 MB
  const size_t need_full = (size_t)2*5*Mtok*4 + (size_t)2*Mtok*CH*2;

  if (ws_size >= need_full) {
    float* wh = (float*)d_ws;
    float* ww = wh + (size_t)5*Mtok;
    unsigned short* hid  = (unsigned short*)(ww + (size_t)5*Mtok);
    unsigned short* hid2 = hid + (size_t)Mtok*CH;
    k_gate_h<<<Mtok/256, 256, 0, stream>>>(x, gh_w, gh_b, wh, 0, Mtok);
    k_fc1<<<dim3(Mtok/64, 6), 256, 0, stream>>>(x, wh, fc1_w, fc1_b, hid, 0, Mtok);
    k_dw<<<Mtok, 128, 0, stream>>>(hid, dw_w, dw_b, gw_w, gw_b, hid2, ww, Mtok);
    k_fc2<<<Mtok/64, 256, 0, stream>>>(hid2, ww, fc2_w, fc2_b, out, 0, Mtok);
  } else {
    // per-image path: 16 images of Mi=16384 tokens; ~25.9 MB of scratch
    const int Mi = 16384;
    float* wh = (float*)d_ws;                               // 5*Mi f32
    float* ww = wh + (size_t)5*Mi;                          // 5*Mi f32
    unsigned short* hid  = (unsigned short*)(ww + (size_t)5*Mi);  // Mi*384 bf16
    unsigned short* hid2 = hid + (size_t)Mi*CH;                   // Mi*384 bf16
    for (int b = 0; b < 16; ++b) {
      int base = b*Mi;
      k_gate_h<<<Mi/256, 256, 0, stream>>>(x, gh_w, gh_b, wh, base, Mi);
      k_fc1<<<dim3(Mi/64, 6), 256, 0, stream>>>(x, wh, fc1_w, fc1_b, hid, base, Mi);
      k_dw<<<Mi, 128, 0, stream>>>(hid, dw_w, dw_b, gw_w, gw_b, hid2, ww, Mi);
      k_fc2<<<Mi/64, 256, 0, stream>>>(hid2, ww, fc2_w, fc2_b, out, base, Mi);
    }
  }
}